// Round 8
// baseline (233.256 us; speedup 1.0000x reference)
//
#include <hip/hip_runtime.h>

#define N_NODES 100000
#define N_EDGES 1600000
#define D 64
#define BK 64                  // dst-nodes per bucket
#define NB2 1563               // ceil(N_NODES/BK)
#define CAP2 1280              // slab slots per bucket (mean 1024, 8 sigma)
#define EPB 4096               // edges per partition block
#define NPART 391              // ceil(N_EDGES/EPB)
#define NREPACK 782            // 6.4M floats / (512*16)

typedef unsigned short ushort_t;
typedef unsigned int uint_t;

__device__ __forceinline__ ushort_t f2bf(float f) {
    uint_t u = __float_as_uint(f);
    u += 0x7FFF + ((u >> 16) & 1);          // round-nearest-even
    return (ushort_t)(u >> 16);
}

// ---------- K1: partition (blocks 0..NPART) + repack (rest) in ONE dispatch ----------
// Partition: LDS counting-sort of 4096 edges by 64-node dst bucket, one
// global atomic per (block,bucket) into gcur (PRE-ZEROED), then
// segment-contiguous slab writes. Repack: feat -> bf16 streaming.
__global__ __launch_bounds__(512) void part_repack(const float* __restrict__ feat,
                                                   ushort_t* __restrict__ featb,
                                                   const int* __restrict__ esrc,
                                                   const int* __restrict__ edst,
                                                   int* __restrict__ gcur,
                                                   int* __restrict__ slab) {
    __shared__ int stage[EPB];              // 16 KB packed, sorted by bucket
    __shared__ ushort_t bkt16[EPB];         // 8 KB
    __shared__ int cnt[NB2];                // 6.25 KB
    __shared__ int cur[NB2];
    __shared__ int gb[NB2];
    __shared__ int s[512];
    const int t = threadIdx.x;

    if (blockIdx.x >= NPART) {              // ---- repack path ----
        const int idx = (blockIdx.x - NPART) * 512 + t;
        const int base = idx * 16;
        if (base < N_NODES * D) {
            const float4* f4 = (const float4*)(feat + base);
            ushort4* o4 = (ushort4*)(featb + base);
#pragma unroll
            for (int j = 0; j < 4; ++j) {
                const float4 v = f4[j];
                o4[j] = make_ushort4(f2bf(v.x), f2bf(v.y), f2bf(v.z), f2bf(v.w));
            }
        }
        return;
    }

    // ---- partition path ----
    const int base = blockIdx.x * EPB;
    const int n = min(EPB, N_EDGES - base);

    for (int i = t; i < NB2; i += 512) cnt[i] = 0;
    __syncthreads();
    for (int i = t; i < n; i += 512)
        atomicAdd(&cnt[edst[base + i] >> 6], 1);
    __syncthreads();
    // exclusive scan over NB2 entries: 4 per thread
    int c0 = 0, c1 = 0, c2 = 0, c3 = 0;
    {
        const int k = 4 * t;
        if (k + 0 < NB2) c0 = cnt[k + 0];
        if (k + 1 < NB2) c1 = cnt[k + 1];
        if (k + 2 < NB2) c2 = cnt[k + 2];
        if (k + 3 < NB2) c3 = cnt[k + 3];
    }
    const int sum = c0 + c1 + c2 + c3;
    s[t] = sum;
    __syncthreads();
    for (int off = 1; off < 512; off <<= 1) {
        const int x = (t >= off) ? s[t - off] : 0;
        __syncthreads();
        s[t] += x;
        __syncthreads();
    }
    int run = s[t] - sum;                   // exclusive prefix
    {
        const int k = 4 * t;
        if (k + 0 < NB2) { cur[k+0] = run; gb[k+0] = (c0 ? atomicAdd(&gcur[k+0], c0) : 0) + (k+0)*CAP2 - run; run += c0; }
        if (k + 1 < NB2) { cur[k+1] = run; gb[k+1] = (c1 ? atomicAdd(&gcur[k+1], c1) : 0) + (k+1)*CAP2 - run; run += c1; }
        if (k + 2 < NB2) { cur[k+2] = run; gb[k+2] = (c2 ? atomicAdd(&gcur[k+2], c2) : 0) + (k+2)*CAP2 - run; run += c2; }
        if (k + 3 < NB2) { cur[k+3] = run; gb[k+3] = (c3 ? atomicAdd(&gcur[k+3], c3) : 0) + (k+3)*CAP2 - run; run += c3; }
    }
    __syncthreads();
    for (int i = t; i < n; i += 512) {      // local sort into stage
        const int d = edst[base + i];
        const int bkt = d >> 6;
        const int pos = atomicAdd(&cur[bkt], 1);
        stage[pos] = ((d & 63) << 17) | esrc[base + i];
        bkt16[pos] = (ushort_t)bkt;
    }
    __syncthreads();
    for (int i = t; i < n; i += 512) {      // segment-contiguous global writes
        const int bkt = bkt16[i];
        const int gp = gb[bkt] + i;
        if (gp < (bkt + 1) * CAP2)          // overflow guard (8-sigma margin)
            slab[gp] = stage[i];
    }
}

// ---------- 8-lane all-reduce on the VALU pipe (DPP, no DS ops) ----------
template<int CTRL>
__device__ __forceinline__ float fadd_dpp(float x) {
    const int r = __builtin_amdgcn_update_dpp(0, __float_as_int(x), CTRL, 0xF, 0xF, true);
    return x + __int_as_float(r);
}
__device__ __forceinline__ float red8(float p) {
    p = fadd_dpp<0xB1>(p);    // quad_perm xor1
    p = fadd_dpp<0x4E>(p);    // quad_perm xor2
    p = fadd_dpp<0x141>(p);   // row_half_mirror
    return p;
}

__device__ __forceinline__ void cvt8(const uint4 u, float* __restrict__ g) {
    g[0] = __uint_as_float(u.x << 16); g[1] = __uint_as_float(u.x & 0xFFFF0000u);
    g[2] = __uint_as_float(u.y << 16); g[3] = __uint_as_float(u.y & 0xFFFF0000u);
    g[4] = __uint_as_float(u.z << 16); g[5] = __uint_as_float(u.z & 0xFFFF0000u);
    g[6] = __uint_as_float(u.w << 16); g[7] = __uint_as_float(u.w & 0xFFFF0000u);
}
__device__ __forceinline__ float cvt_dot(const uint4 u, const float* __restrict__ h,
                                         float* __restrict__ g) {
    cvt8(u, g);
    float p = 0.f;
#pragma unroll
    for (int k = 0; k < 8; ++k) p += g[k] * h[k];
    return p;
}

// ---------- K2: fused SDDMM + SpMM ----------
// One 64-node bucket per 256-thread block (LDS ~11 KB, VGPR ~40 -> high
// occupancy; 1563 blocks = 6.1/CU). Counting-sort to per-node CSR in LDS,
// then 8-lane node slots, bf16 gathers, unroll-4 MLP, register accumulate.
__global__ __launch_bounds__(256) void fused_spmm(const uint4* __restrict__ featb4,
                                                  const int* __restrict__ slab,
                                                  const int* __restrict__ gcur,
                                                  float4* __restrict__ neigh4) {
    __shared__ int seA[CAP2];               // 5 KB raw packed
    __shared__ int seB[CAP2];               // 5 KB srcs sorted by local dst
    __shared__ int kcnt[64];
    __shared__ int kcur[64];
    __shared__ int rowoff[65];
    const int t = threadIdx.x;
    const int b = blockIdx.x;
    const int nbase = b * BK;
    const int nb_nodes = min(BK, N_NODES - nbase);
    const int sbase = b * CAP2;
    const int ne = min(gcur[b], CAP2);

    for (int i = t; i < ne; i += 256) seA[i] = slab[sbase + i];
    if (t < 64) kcnt[t] = 0;
    __syncthreads();
    for (int i = t; i < ne; i += 256)
        atomicAdd(&kcnt[seA[i] >> 17], 1);
    __syncthreads();
    const int v = (t < 64) ? kcnt[t] : 0;
    if (t < 64) kcur[t] = v;
    __syncthreads();
    for (int off = 1; off < 64; off <<= 1) {
        const int x = (t >= off && t < 64) ? kcur[t - off] : 0;
        __syncthreads();
        if (t < 64) kcur[t] += x;
        __syncthreads();
    }
    if (t < 64) rowoff[t] = kcur[t] - v;    // exclusive
    if (t == 0) rowoff[64] = ne;
    __syncthreads();
    if (t < 64) kcur[t] = rowoff[t];
    __syncthreads();
    for (int i = t; i < ne; i += 256) {
        const int pk = seA[i];
        const int pos = atomicAdd(&kcur[pk >> 17], 1);
        seB[pos] = pk & 0x1FFFF;
    }
    __syncthreads();

    const int slot = t >> 3;                // 32 node-slots per block
    const int l = t & 7;                    // lane owns dims 8l..8l+7
#pragma unroll
    for (int ln0 = 0; ln0 < BK; ln0 += 32) {
        const int ln = ln0 + slot;
        if (ln >= nb_nodes) continue;       // no barriers below: safe
        const int nidx = nbase + ln;
        float h[8];
        cvt8(featb4[nidx * 8 + l], h);
        float acc[8];
#pragma unroll
        for (int k = 0; k < 8; ++k) acc[k] = 0.f;

        int e = rowoff[ln];
        const int e1 = rowoff[ln + 1];
        for (; e + 3 < e1; e += 4) {
            const int s0 = seB[e], s1 = seB[e + 1], s2 = seB[e + 2], s3 = seB[e + 3];
            const uint4 u0 = featb4[s0 * 8 + l];   // 4 gathers in flight
            const uint4 u1 = featb4[s1 * 8 + l];
            const uint4 u2 = featb4[s2 * 8 + l];
            const uint4 u3 = featb4[s3 * 8 + l];
            float g0[8], g1[8], g2[8], g3[8];
            float p0 = cvt_dot(u0, h, g0);
            float p1 = cvt_dot(u1, h, g1);
            float p2 = cvt_dot(u2, h, g2);
            float p3 = cvt_dot(u3, h, g3);
            p0 = red8(p0); p1 = red8(p1); p2 = red8(p2); p3 = red8(p3);
#pragma unroll
            for (int k = 0; k < 8; ++k)
                acc[k] += g0[k] * p0 + g1[k] * p1 + g2[k] * p2 + g3[k] * p3;
        }
        for (; e < e1; ++e) {
            const uint4 u0 = featb4[seB[e] * 8 + l];
            float g0[8];
            float p0 = red8(cvt_dot(u0, h, g0));
#pragma unroll
            for (int k = 0; k < 8; ++k) acc[k] += g0[k] * p0;
        }
        neigh4[nidx * 16 + 2 * l]     = make_float4(acc[0], acc[1], acc[2], acc[3]);
        neigh4[nidx * 16 + 2 * l + 1] = make_float4(acc[4], acc[5], acc[6], acc[7]);
    }
}

// ---------- K3: in-place GEMM, barrier-free broadcast design ----------
// 64-row tile per block. Thread = (o = t&63, rg = t>>6); wave rg owns rows
// r === rg (mod 4) exclusively -> in-place safe without barriers. W row o in
// VGPRs; neigh row elements read wave-uniform (L1 broadcast).
__global__ __launch_bounds__(256) void gemm_bcast(float* __restrict__ out,
                                                  const float* __restrict__ W) {
    const int t = threadIdx.x;
    const int o = t & 63;
    const int rg = t >> 6;                  // 0..3
    const int base = blockIdx.x * BK;
    const int rows = min(BK, N_NODES - base);

    float wcol[D];
    {
        const float4* W4 = (const float4*)(W + o * D);
#pragma unroll
        for (int i4 = 0; i4 < 16; ++i4) {
            const float4 w = W4[i4];
            wcol[4*i4+0] = w.x; wcol[4*i4+1] = w.y;
            wcol[4*i4+2] = w.z; wcol[4*i4+3] = w.w;
        }
    }
    for (int r = rg; r < rows; r += 4) {
        const float4* arow = (const float4*)(out + (long)(base + r) * D);
        float sumv = 0.f;
#pragma unroll
        for (int i4 = 0; i4 < 16; ++i4) {
            const float4 a4 = arow[i4];     // wave-uniform address: broadcast
            sumv += a4.x * wcol[4*i4+0];
            sumv += a4.y * wcol[4*i4+1];
            sumv += a4.z * wcol[4*i4+2];
            sumv += a4.w * wcol[4*i4+3];
        }
        out[(long)(base + r) * D + o] = sumv;   // coalesced per wave
    }
}

extern "C" void kernel_launch(void* const* d_in, const int* in_sizes, int n_in,
                              void* d_out, int out_size, void* d_ws, size_t ws_size,
                              hipStream_t stream) {
    const float* feat = (const float*)d_in[0];
    const int*   esrc = (const int*)d_in[1];
    const int*   edst = (const int*)d_in[2];
    const float* W    = (const float*)d_in[3];
    float* out = (float*)d_out;

    char* ws = (char*)d_ws;
    ushort_t* featb = (ushort_t*)(ws);                      // 12.8 MB
    int* slab = (int*)(ws + 12800000);                      // NB2*CAP2*4 = 8.0 MB
    int* gcur = (int*)(ws + 12800000 + (size_t)NB2 * CAP2 * 4);  // 6.25 KB

    hipMemsetAsync(gcur, 0, NB2 * sizeof(int), stream);
    part_repack<<<NPART + NREPACK, 512, 0, stream>>>(feat, featb, esrc, edst, gcur, slab);
    fused_spmm<<<NB2, 256, 0, stream>>>((const uint4*)featb, slab, gcur, (float4*)out);
    gemm_bcast<<<NB2, 256, 0, stream>>>(out, W);
}